// Round 17
// baseline (56.859 us; speedup 1.0000x reference)
//
#include <hip/hip_runtime.h>

#define DIM 256
#define T_LEN 4096
#define K_CODES 1024
#define N_TOK 65536
#define NELEM 16777216

// ws layout (32-bit units):
//   [0,1024)       cnh2[k] packed (bf16_hi | bf16_lo<<16) of 128 + 128*|e_k|^2
//   [4096,69632)   cbb8: fp8(256*cb), MX-tiled 256 KB (r14 layout):
//                  byte = ci*8192 + wnd*2048 + hs*1024 + half*512 + r*16 + off
// Score: s' = 128 + 128|e|^2 - 256*(e_fp8 . x_fp8) in ~[80,180] > 0.
// Loss accumulated via atomicAdd into out[NELEM] (zeroed by hipMemsetAsync).

typedef __attribute__((ext_vector_type(8))) short bf16x8;
typedef __attribute__((ext_vector_type(16))) float f32x16;
typedef __attribute__((ext_vector_type(8))) int i32x8;

__device__ __forceinline__ unsigned short f2bf(float f) {
    unsigned u = __builtin_bit_cast(unsigned, f);
    return (unsigned short)((u + 0x7FFFu + ((u >> 16) & 1u)) >> 16);
}
__device__ __forceinline__ float bf2f(unsigned short h) {
    return __builtin_bit_cast(float, (unsigned)h << 16);
}
__device__ __forceinline__ unsigned f2u(float f) { return __builtin_bit_cast(unsigned, f); }
__device__ __forceinline__ float u2f(unsigned u) { return __builtin_bit_cast(float, u); }
__device__ __forceinline__ unsigned umin2(unsigned a, unsigned b) { return a < b ? a : b; }

union FragU { bf16x8 v; unsigned short u[8]; };

#define GLLOAD(gsrc, lbase)                                                              \
    __builtin_amdgcn_global_load_lds(                                                    \
        (const __attribute__((address_space(1))) unsigned int*)(gsrc),                   \
        (__attribute__((address_space(3))) unsigned int*)(lbase), 16, 0, 0)

__device__ __forceinline__ unsigned cvt8n(float a, float b) {
    unsigned r;
    asm("v_cvt_pk_fp8_f32 %0, -%1, -%2" : "=v"(r) : "v"(a), "v"(b));
    return r;
}
__device__ __forceinline__ unsigned cvt8(float a, float b) {
    unsigned r;
    asm("v_cvt_pk_fp8_f32 %0, %1, %2" : "=v"(r) : "v"(a), "v"(b));
    return r;
}

// ---------------- prep: cb -> fp8(256x, MX-tiled) + cnh2 (r14-identical) ----------------
__global__ __launch_bounds__(256) void prep(const float* __restrict__ cb,
                                            char* __restrict__ cbb8,
                                            unsigned* __restrict__ cnh2) {
    const int k = blockIdx.x * 4 + (threadIdx.x >> 6);
    const int lane = threadIdx.x & 63;
    float4 v = *reinterpret_cast<const float4*>(cb + (size_t)k * DIM + lane * 4);
    float s = v.x * v.x + v.y * v.y + v.z * v.z + v.w * v.w;
    #pragma unroll
    for (int off = 32; off; off >>= 1) s += __shfl_down(s, off);
    if (lane == 0) {
        float cn = 128.0f + 128.0f * s;
        unsigned short chi = f2bf(cn);
        unsigned short clo = f2bf(cn - bf2f(chi));
        cnh2[k] = (unsigned)chi | ((unsigned)clo << 16);
    }
    const unsigned wlo = cvt8(256.0f * v.x, 256.0f * v.y);
    const unsigned whi = cvt8(256.0f * v.z, 256.0f * v.w);
    const unsigned dw = __builtin_amdgcn_perm(whi, wlo, 0x05040100u);
    const int d0 = lane * 4;
    const int wnd = d0 >> 6, dwi = d0 & 63, hs = dwi >> 5, i = dwi & 31;
    const int byte = (k >> 5) * 8192 + wnd * 2048 + hs * 1024 + (i >> 4) * 512
                   + (k & 31) * 16 + (i & 15);
    *reinterpret_cast<unsigned*>(cbb8 + byte) = dw;
}

// ---------------- fused: MX-fp8 argmin + scatter + loss ----------------
// r14 skeleton; sweep upgraded: TRI-buffered staging -> ONE barrier/round
// (write target's last readers were 2 rounds ago; skew<=1 enforced by the
// single barrier), and 4 independent MFMA chains (accP/accQ per token group).
__global__ __launch_bounds__(256, 2) void vq_fused(const float* __restrict__ x,
                                                   const char* __restrict__ cbb8,
                                                   const unsigned* __restrict__ cnh2,
                                                   const float* __restrict__ cbf,
                                                   float* __restrict__ out,
                                                   float* __restrict__ loss) {
    __shared__ __align__(16) char ring[49152];        // x-tile(32K) / 3x16KB staging / fs
    __shared__ unsigned cnl[1024];
    __shared__ unsigned kbx[4][64];
    __shared__ int kkl[128];
    __shared__ float wsum[4];
    const int tid = threadIdx.x;
    const int w = tid >> 6, lane = tid & 63, hi = lane >> 5, ln31 = lane & 31;
    const int tg = w >> 1, kh = w & 1;
    const int tw0 = blockIdx.x * 128;
    const int b = tw0 >> 12, tb = tw0 & (T_LEN - 1);

    cnl[tid] = cnh2[tid];
    cnl[tid + 256] = cnh2[tid + 256];
    cnl[tid + 512] = cnh2[tid + 512];
    cnl[tid + 768] = cnh2[tid + 768];

    // ---- x ingest: [128 t][256 d] fp8 tile (32 KB), negated, 8B-granule XOR ----
    const int tqi = tid & 31, cqi = tid >> 5;
    const float* xb = x + (size_t)b * DIM * T_LEN + tb + 4 * tqi;
    float x2s = 0.0f;
    #pragma unroll
    for (int ii = 0; ii < 8; ++ii) {
        const int cl = (ii * 8 + cqi) * 4;
        const float* p = xb + (size_t)cl * T_LEN;
        const float4 P0 = *reinterpret_cast<const float4*>(p);
        const float4 P1 = *reinterpret_cast<const float4*>(p + T_LEN);
        const float4 P2 = *reinterpret_cast<const float4*>(p + 2 * T_LEN);
        const float4 P3 = *reinterpret_cast<const float4*>(p + 3 * T_LEN);
        x2s = fmaf(P0.x, P0.x, fmaf(P0.y, P0.y, fmaf(P0.z, P0.z, fmaf(P0.w, P0.w, x2s))));
        x2s = fmaf(P1.x, P1.x, fmaf(P1.y, P1.y, fmaf(P1.z, P1.z, fmaf(P1.w, P1.w, x2s))));
        x2s = fmaf(P2.x, P2.x, fmaf(P2.y, P2.y, fmaf(P2.z, P2.z, fmaf(P2.w, P2.w, x2s))));
        x2s = fmaf(P3.x, P3.x, fmaf(P3.y, P3.y, fmaf(P3.z, P3.z, fmaf(P3.w, P3.w, x2s))));
        const unsigned lo0 = cvt8n(P0.x, P0.y), hi0 = cvt8n(P0.z, P0.w);
        const unsigned lo1 = cvt8n(P1.x, P1.y), hi1 = cvt8n(P1.z, P1.w);
        const unsigned lo2 = cvt8n(P2.x, P2.y), hi2 = cvt8n(P2.z, P2.w);
        const unsigned lo3 = cvt8n(P3.x, P3.y), hi3 = cvt8n(P3.z, P3.w);
        const unsigned s01 = __builtin_amdgcn_perm(lo1, lo0, 0x05010400u);
        const unsigned s23 = __builtin_amdgcn_perm(lo3, lo2, 0x05010400u);
        const unsigned u01 = __builtin_amdgcn_perm(hi1, hi0, 0x05010400u);
        const unsigned u23 = __builtin_amdgcn_perm(hi3, hi2, 0x05010400u);
        const unsigned t0 = __builtin_amdgcn_perm(s23, s01, 0x05040100u);
        const unsigned t1 = __builtin_amdgcn_perm(s23, s01, 0x07060302u);
        const unsigned t2 = __builtin_amdgcn_perm(u23, u01, 0x05040100u);
        const unsigned t3 = __builtin_amdgcn_perm(u23, u01, 0x07060302u);
        const int ta = 4 * tqi;
        *reinterpret_cast<unsigned*>(ring + (ta + 0) * 256 + (cl ^ (((ta + 0) & 15) << 3))) = t0;
        *reinterpret_cast<unsigned*>(ring + (ta + 1) * 256 + (cl ^ (((ta + 1) & 15) << 3))) = t1;
        *reinterpret_cast<unsigned*>(ring + (ta + 2) * 256 + (cl ^ (((ta + 2) & 15) << 3))) = t2;
        *reinterpret_cast<unsigned*>(ring + (ta + 3) * 256 + (cl ^ (((ta + 3) & 15) << 3))) = t3;
    }
    __syncthreads();

    // ---- xf frags: B-operand, 4 K-windows; lane = (token=l&31, k=(l>>5)*32+i) ----
    i32x8 xf0[4], xf1[4];
    {
        const int tp0 = tg * 64 + ln31, tp1 = tg * 64 + 32 + ln31;
        const int z0 = (tp0 & 15) << 3, z1 = (tp1 & 15) << 3;
        #pragma unroll
        for (int wnd = 0; wnd < 4; ++wnd) {
            #pragma unroll
            for (int g = 0; g < 4; ++g) {
                const int o = wnd * 64 + hi * 32 + g * 8;
                const long v0 = *reinterpret_cast<const long*>(ring + tp0 * 256 + (o ^ z0));
                const long v1 = *reinterpret_cast<const long*>(ring + tp1 * 256 + (o ^ z1));
                xf0[wnd][2 * g] = (int)(unsigned)(v0 & 0xFFFFFFFFu);
                xf0[wnd][2 * g + 1] = (int)(unsigned)(((unsigned long)v0) >> 32);
                xf1[wnd][2 * g] = (int)(unsigned)(v1 & 0xFFFFFFFFu);
                xf1[wnd][2 * g + 1] = (int)(unsigned)(((unsigned long)v1) >> 32);
            }
        }
    }
    __syncthreads();                                  // ring free for staging

    // ---- staging: chunks kc (kh0) and 16+kc (kh1) -> one 16 KB tri-buffer slot ----
    auto stage = [&](int kc, int buf) {
        char* lb = ring + buf * 16384 + w * 1024;
        const char* gc = cbb8 + kc * 8192;
        #pragma unroll
        for (int j = 0; j < 4; ++j) {
            const int o = j * 4096 + tid * 16;
            GLLOAD(gc + (o & 8191) + (o >> 13) * 131072, lb + j * 4096);
        }
    };
    stage(0, 0);

    FragU onef;
    #pragma unroll
    for (int i = 0; i < 8; ++i) onef.u[i] = (hi == 0 && i < 2) ? 0x3F80 : 0;

    unsigned b0a = 0xFFFFFFFFu, b0b = 0xFFFFFFFFu;
    unsigned b1a = 0xFFFFFFFFu, b1b = 0xFFFFFFFFu;

    for (int kc = 0; kc < 16; ++kc) {
        const int cur = kc % 3;
        if (kc < 15) {
            stage(kc + 1, (kc + 1) % 3);
            asm volatile("s_waitcnt vmcnt(4)" ::: "memory");   // round kc's slot landed
        } else {
            asm volatile("s_waitcnt vmcnt(0)" ::: "memory");
        }
        __builtin_amdgcn_s_barrier();                 // single barrier per round
        __builtin_amdgcn_sched_barrier(0);

        const unsigned d = cnl[kh * 512 + kc * 32 + ln31];
        FragU cfr0;
        #pragma unroll
        for (int i = 0; i < 8; ++i) cfr0.u[i] = 0;
        if (hi == 0) {
            cfr0.u[0] = (unsigned short)(d & 0xFFFFu);
            cfr0.u[1] = (unsigned short)(d >> 16);
        }

        // A frags: all 4 windows up front (8 x b128, conflict-free)
        const char* cbpA = ring + cur * 16384 + kh * 8192 + hi * 1024 + ln31 * 16;
        i32x8 aw[4];
        #pragma unroll
        for (int wnd = 0; wnd < 4; ++wnd) {
            const uint4 alo = *reinterpret_cast<const uint4*>(cbpA + wnd * 2048);
            const uint4 ahi = *reinterpret_cast<const uint4*>(cbpA + wnd * 2048 + 512);
            aw[wnd][0] = (int)alo.x; aw[wnd][1] = (int)alo.y;
            aw[wnd][2] = (int)alo.z; aw[wnd][3] = (int)alo.w;
            aw[wnd][4] = (int)ahi.x; aw[wnd][5] = (int)ahi.y;
            aw[wnd][6] = (int)ahi.z; aw[wnd][7] = (int)ahi.w;
        }

        // 4 independent MFMA chains: accP (cn + wnd0 + wnd1), accQ (wnd2 + wnd3)
        f32x16 accP0, accQ0, accP1, accQ1;
        #pragma unroll
        for (int i = 0; i < 16; ++i) { accP0[i] = 0.0f; accQ0[i] = 0.0f;
                                       accP1[i] = 0.0f; accQ1[i] = 0.0f; }
        accP0 = __builtin_amdgcn_mfma_f32_32x32x16_bf16(cfr0.v, onef.v, accP0, 0, 0, 0);
        accP1 = __builtin_amdgcn_mfma_f32_32x32x16_bf16(cfr0.v, onef.v, accP1, 0, 0, 0);
        accQ0 = __builtin_amdgcn_mfma_scale_f32_32x32x64_f8f6f4(
            aw[2], xf0[2], accQ0, 0, 0, 0, 0x7F7F7F7F, 0, 0x7F7F7F7F);
        accQ1 = __builtin_amdgcn_mfma_scale_f32_32x32x64_f8f6f4(
            aw[2], xf1[2], accQ1, 0, 0, 0, 0x7F7F7F7F, 0, 0x7F7F7F7F);
        accP0 = __builtin_amdgcn_mfma_scale_f32_32x32x64_f8f6f4(
            aw[0], xf0[0], accP0, 0, 0, 0, 0x7F7F7F7F, 0, 0x7F7F7F7F);
        accP1 = __builtin_amdgcn_mfma_scale_f32_32x32x64_f8f6f4(
            aw[0], xf1[0], accP1, 0, 0, 0, 0x7F7F7F7F, 0, 0x7F7F7F7F);
        accQ0 = __builtin_amdgcn_mfma_scale_f32_32x32x64_f8f6f4(
            aw[3], xf0[3], accQ0, 0, 0, 0, 0x7F7F7F7F, 0, 0x7F7F7F7F);
        accQ1 = __builtin_amdgcn_mfma_scale_f32_32x32x64_f8f6f4(
            aw[3], xf1[3], accQ1, 0, 0, 0, 0x7F7F7F7F, 0, 0x7F7F7F7F);
        accP0 = __builtin_amdgcn_mfma_scale_f32_32x32x64_f8f6f4(
            aw[1], xf0[1], accP0, 0, 0, 0, 0x7F7F7F7F, 0, 0x7F7F7F7F);
        accP1 = __builtin_amdgcn_mfma_scale_f32_32x32x64_f8f6f4(
            aw[1], xf1[1], accP1, 0, 0, 0, 0x7F7F7F7F, 0, 0x7F7F7F7F);

        const int kbl = kh * 512 + kc * 32 + hi * 4;
        #pragma unroll
        for (int rg = 0; rg < 16; ++rg) {
            const unsigned kk = (unsigned)(kbl + (rg & 3) + 8 * (rg >> 2));
            const unsigned p0 = (f2u(accP0[rg] + accQ0[rg]) & 0xFFFFFC00u) | kk;
            const unsigned p1 = (f2u(accP1[rg] + accQ1[rg]) & 0xFFFFFC00u) | kk;
            if (rg & 1) { b0b = umin2(b0b, p0); b1b = umin2(b1b, p1); }
            else        { b0a = umin2(b0a, p0); b1a = umin2(b1a, p1); }
        }
        // no second barrier: tri-buffer guarantees next stage target is 2-rounds stale
    }

    // merge chains + hi-halves
    unsigned best0 = umin2(b0a, b0b);
    unsigned best1 = umin2(b1a, b1b);
    best0 = umin2(best0, __shfl_xor(best0, 32));
    best1 = umin2(best1, __shfl_xor(best1, 32));
    if (hi == 0) { kbx[w][ln31] = best0; kbx[w][32 + ln31] = best1; }
    __syncthreads();

    float red = x2s;
    if (kh == 0) {                    // merge K-halves; token = tw0 + tg*64 + lane
        const unsigned key = umin2(kbx[w][lane], kbx[w + 1][lane]);
        kkl[tg * 64 + lane] = (int)(key & 1023u);
        red += (u2f(key & 0xFFFFFC00u) - 128.0f) * 0.0078125f;
    }
    #pragma unroll
    for (int off = 32; off; off >>= 1) red += __shfl_down(red, off);
    if (lane == 0) wsum[w] = red;
    __syncthreads();
    if (tid == 0)
        atomicAdd(loss, (wsum[0] + wsum[1] + wsum[2] + wsum[3]) * (2.0f / (float)NELEM));

    // ---- fused scatter: 8 slices of 32 c through [32][132] f32 tile ----
    float* fs = (float*)ring;
    const int tt = tid & 127, ch = tid >> 7;
    const size_t rowb = (size_t)kkl[tt] * DIM;
    #pragma unroll 1
    for (int sl = 0; sl < 8; ++sl) {
        float4 g[4];
        #pragma unroll
        for (int i = 0; i < 4; ++i)
            g[i] = *reinterpret_cast<const float4*>(cbf + rowb + sl * 32 + ch * 16 + 4 * i);
        __syncthreads();
        #pragma unroll
        for (int i = 0; i < 4; ++i) {
            const int c0 = ch * 16 + 4 * i;
            fs[(c0 + 0) * 132 + tt] = g[i].x;
            fs[(c0 + 1) * 132 + tt] = g[i].y;
            fs[(c0 + 2) * 132 + tt] = g[i].z;
            fs[(c0 + 3) * 132 + tt] = g[i].w;
        }
        __syncthreads();
        #pragma unroll
        for (int p = 0; p < 4; ++p) {
            const int c = tid >> 3, tq = (tid & 7) + p * 8;
            const float4 v = *reinterpret_cast<const float4*>(fs + c * 132 + tq * 4);
            *reinterpret_cast<float4*>(
                out + (((size_t)(b * DIM + sl * 32 + c)) << 12) + tb + tq * 4) = v;
        }
    }
}

extern "C" void kernel_launch(void* const* d_in, const int* in_sizes, int n_in,
                              void* d_out, int out_size, void* d_ws, size_t ws_size,
                              hipStream_t stream) {
    const float* x  = (const float*)d_in[0];    // [16,256,4096]
    const float* cb = (const float*)d_in[1];    // [1024,256]
    float* out = (float*)d_out;                 // quant (16777216) + loss (1)
    unsigned* ws = (unsigned*)d_ws;
    unsigned* cnh2 = ws;                        // 1024 u32
    char* cbb8 = (char*)(ws + 4096);            // 256 KB fp8 codebook (MX-tiled)

    hipMemsetAsync(out + NELEM, 0, 4, stream);  // zero loss accumulator (every call)
    prep<<<K_CODES / 4, 256, 0, stream>>>(cb, cbb8, cnh2);
    vq_fused<<<N_TOK / 128, 256, 0, stream>>>(x, cbb8, cnh2, cb, out, out + NELEM);
}

// Round 18
// 53.521 us; speedup vs baseline: 1.0624x; 1.0624x over previous
//
#include <hip/hip_runtime.h>

#define DIM 256
#define T_LEN 4096
#define K_CODES 1024
#define N_TOK 65536
#define NELEM 16777216

// ws layout (32-bit units):
//   [0,1024)       cnh2[k] packed (bf16_hi | bf16_lo<<16) of 128 + 128*|e_k|^2
//   [4096,69632)   cbb8: fp8(256*cb), MX-tiled 256 KB (r14 layout):
//                  byte = ci*8192 + wnd*2048 + hs*1024 + half*512 + r*16 + off
// Score: s' = 128 + 128|e|^2 - 256*(e_fp8 . x_fp8) in ~[80,180] > 0.
// Loss accumulated via atomicAdd into out[NELEM] (zeroed by hipMemsetAsync).

typedef __attribute__((ext_vector_type(8))) short bf16x8;
typedef __attribute__((ext_vector_type(16))) float f32x16;
typedef __attribute__((ext_vector_type(8))) int i32x8;

__device__ __forceinline__ unsigned short f2bf(float f) {     // RNE f32->bf16
    unsigned u = __builtin_bit_cast(unsigned, f);
    return (unsigned short)((u + 0x7FFFu + ((u >> 16) & 1u)) >> 16);
}
__device__ __forceinline__ float bf2f(unsigned short h) {
    return __builtin_bit_cast(float, (unsigned)h << 16);
}
__device__ __forceinline__ unsigned f2u(float f) { return __builtin_bit_cast(unsigned, f); }
__device__ __forceinline__ float u2f(unsigned u) { return __builtin_bit_cast(float, u); }
__device__ __forceinline__ unsigned umin2(unsigned a, unsigned b) { return a < b ? a : b; }

union FragU { bf16x8 v; unsigned short u[8]; };

#define GLLOAD(gsrc, lbase)                                                              \
    __builtin_amdgcn_global_load_lds(                                                    \
        (const __attribute__((address_space(1))) unsigned int*)(gsrc),                   \
        (__attribute__((address_space(3))) unsigned int*)(lbase), 16, 0, 0)

// two f32 -> 2 fp8 e4m3 (bytes 0,1), negated / plain
__device__ __forceinline__ unsigned cvt8n(float a, float b) {
    unsigned r;
    asm("v_cvt_pk_fp8_f32 %0, -%1, -%2" : "=v"(r) : "v"(a), "v"(b));
    return r;
}
__device__ __forceinline__ unsigned cvt8(float a, float b) {
    unsigned r;
    asm("v_cvt_pk_fp8_f32 %0, %1, %2" : "=v"(r) : "v"(a), "v"(b));
    return r;
}

// ---------------- prep: cb -> fp8(256x, MX-tiled) + cnh2 (r14-identical) ----------------
__global__ __launch_bounds__(256) void prep(const float* __restrict__ cb,
                                            char* __restrict__ cbb8,
                                            unsigned* __restrict__ cnh2) {
    const int k = blockIdx.x * 4 + (threadIdx.x >> 6);
    const int lane = threadIdx.x & 63;
    float4 v = *reinterpret_cast<const float4*>(cb + (size_t)k * DIM + lane * 4);
    float s = v.x * v.x + v.y * v.y + v.z * v.z + v.w * v.w;
    #pragma unroll
    for (int off = 32; off; off >>= 1) s += __shfl_down(s, off);
    if (lane == 0) {
        float cn = 128.0f + 128.0f * s;
        unsigned short chi = f2bf(cn);
        unsigned short clo = f2bf(cn - bf2f(chi));
        cnh2[k] = (unsigned)chi | ((unsigned)clo << 16);
    }
    const unsigned wlo = cvt8(256.0f * v.x, 256.0f * v.y);
    const unsigned whi = cvt8(256.0f * v.z, 256.0f * v.w);
    const unsigned dw = __builtin_amdgcn_perm(whi, wlo, 0x05040100u);
    const int d0 = lane * 4;
    const int wnd = d0 >> 6, dwi = d0 & 63, hs = dwi >> 5, i = dwi & 31;
    const int byte = (k >> 5) * 8192 + wnd * 2048 + hs * 1024 + (i >> 4) * 512
                   + (k & 31) * 16 + (i & 15);
    *reinterpret_cast<unsigned*>(cbb8 + byte) = dw;
}

// ---------------- fused: MX-fp8 argmin sweep + scatter + loss (r14 structure) ----------------
// 512 blocks x 4 waves (2 tg x 2 kh), 64 tokens/wave, 16 rounds, counted vmcnt(4)
// + raw barriers, double-buffered 2x16KB staging, fused scatter. Loss fused via
// atomicAdd (proven r17); ingest |x|^2 chain split 4-way (latency only).
__global__ __launch_bounds__(256, 2) void vq_fused(const float* __restrict__ x,
                                                   const char* __restrict__ cbb8,
                                                   const unsigned* __restrict__ cnh2,
                                                   const float* __restrict__ cbf,
                                                   float* __restrict__ out,
                                                   float* __restrict__ loss) {
    __shared__ __align__(16) char ring[32768];        // x-tile / 2x16KB dbuf / scatter
    __shared__ unsigned cnl[1024];
    __shared__ unsigned kbx[4][64];
    __shared__ int kkl[128];
    __shared__ float wsum[4];
    const int tid = threadIdx.x;
    const int w = tid >> 6, lane = tid & 63, hi = lane >> 5, ln31 = lane & 31;
    const int tg = w >> 1, kh = w & 1;
    const int tw0 = blockIdx.x * 128;
    const int b = tw0 >> 12, tb = tw0 & (T_LEN - 1);

    cnl[tid] = cnh2[tid];
    cnl[tid + 256] = cnh2[tid + 256];
    cnl[tid + 512] = cnh2[tid + 512];
    cnl[tid + 768] = cnh2[tid + 768];

    // ---- x ingest: [128 t][256 d] fp8 tile (32 KB), negated, 8B-granule XOR ----
    const int tqi = tid & 31, cqi = tid >> 5;         // 32 t-quads x 8 c-octs
    const float* xb = x + (size_t)b * DIM * T_LEN + tb + 4 * tqi;
    float x2a = 0.0f, x2b = 0.0f, x2c = 0.0f, x2d = 0.0f;   // 4 independent chains
    #pragma unroll
    for (int ii = 0; ii < 8; ++ii) {
        const int cl = (ii * 8 + cqi) * 4;            // dim quad 0..252
        const float* p = xb + (size_t)cl * T_LEN;
        const float4 P0 = *reinterpret_cast<const float4*>(p);
        const float4 P1 = *reinterpret_cast<const float4*>(p + T_LEN);
        const float4 P2 = *reinterpret_cast<const float4*>(p + 2 * T_LEN);
        const float4 P3 = *reinterpret_cast<const float4*>(p + 3 * T_LEN);
        x2a = fmaf(P0.x, P0.x, fmaf(P0.y, P0.y, fmaf(P0.z, P0.z, fmaf(P0.w, P0.w, x2a))));
        x2b = fmaf(P1.x, P1.x, fmaf(P1.y, P1.y, fmaf(P1.z, P1.z, fmaf(P1.w, P1.w, x2b))));
        x2c = fmaf(P2.x, P2.x, fmaf(P2.y, P2.y, fmaf(P2.z, P2.z, fmaf(P2.w, P2.w, x2c))));
        x2d = fmaf(P3.x, P3.x, fmaf(P3.y, P3.y, fmaf(P3.z, P3.z, fmaf(P3.w, P3.w, x2d))));
        const unsigned lo0 = cvt8n(P0.x, P0.y), hi0 = cvt8n(P0.z, P0.w);
        const unsigned lo1 = cvt8n(P1.x, P1.y), hi1 = cvt8n(P1.z, P1.w);
        const unsigned lo2 = cvt8n(P2.x, P2.y), hi2 = cvt8n(P2.z, P2.w);
        const unsigned lo3 = cvt8n(P3.x, P3.y), hi3 = cvt8n(P3.z, P3.w);
        const unsigned s01 = __builtin_amdgcn_perm(lo1, lo0, 0x05010400u);
        const unsigned s23 = __builtin_amdgcn_perm(lo3, lo2, 0x05010400u);
        const unsigned u01 = __builtin_amdgcn_perm(hi1, hi0, 0x05010400u);
        const unsigned u23 = __builtin_amdgcn_perm(hi3, hi2, 0x05010400u);
        const unsigned t0 = __builtin_amdgcn_perm(s23, s01, 0x05040100u);
        const unsigned t1 = __builtin_amdgcn_perm(s23, s01, 0x07060302u);
        const unsigned t2 = __builtin_amdgcn_perm(u23, u01, 0x05040100u);
        const unsigned t3 = __builtin_amdgcn_perm(u23, u01, 0x07060302u);
        const int ta = 4 * tqi;
        *reinterpret_cast<unsigned*>(ring + (ta + 0) * 256 + (cl ^ (((ta + 0) & 15) << 3))) = t0;
        *reinterpret_cast<unsigned*>(ring + (ta + 1) * 256 + (cl ^ (((ta + 1) & 15) << 3))) = t1;
        *reinterpret_cast<unsigned*>(ring + (ta + 2) * 256 + (cl ^ (((ta + 2) & 15) << 3))) = t2;
        *reinterpret_cast<unsigned*>(ring + (ta + 3) * 256 + (cl ^ (((ta + 3) & 15) << 3))) = t3;
    }
    float x2s = (x2a + x2b) + (x2c + x2d);
    __syncthreads();

    // ---- xf frags: B-operand, 4 K-windows; lane = (token=l&31, k=(l>>5)*32+i) ----
    i32x8 xf0[4], xf1[4];                             // 64 VGPR total
    {
        const int tp0 = tg * 64 + ln31, tp1 = tg * 64 + 32 + ln31;
        const int z0 = (tp0 & 15) << 3, z1 = (tp1 & 15) << 3;
        #pragma unroll
        for (int wnd = 0; wnd < 4; ++wnd) {
            #pragma unroll
            for (int g = 0; g < 4; ++g) {
                const int o = wnd * 64 + hi * 32 + g * 8;
                const long v0 = *reinterpret_cast<const long*>(ring + tp0 * 256 + (o ^ z0));
                const long v1 = *reinterpret_cast<const long*>(ring + tp1 * 256 + (o ^ z1));
                xf0[wnd][2 * g] = (int)(unsigned)(v0 & 0xFFFFFFFFu);
                xf0[wnd][2 * g + 1] = (int)(unsigned)(((unsigned long)v0) >> 32);
                xf1[wnd][2 * g] = (int)(unsigned)(v1 & 0xFFFFFFFFu);
                xf1[wnd][2 * g + 1] = (int)(unsigned)(((unsigned long)v1) >> 32);
            }
        }
    }
    __syncthreads();                                  // ring free for staging

    // ---- staging: chunks kc (kh0) and 16+kc (kh1) -> 16 KB, linear copy ----
    auto stage = [&](int kc, int buf) {
        char* lb = ring + buf * 16384 + w * 1024;
        const char* gc = cbb8 + kc * 8192;
        #pragma unroll
        for (int j = 0; j < 4; ++j) {
            const int o = j * 4096 + tid * 16;
            GLLOAD(gc + (o & 8191) + (o >> 13) * 131072, lb + j * 4096);
        }
    };
    stage(0, 0);

    FragU cfr0, onef;                                 // bf16 cn-fold operands
    #pragma unroll
    for (int i = 0; i < 8; ++i) onef.u[i] = (hi == 0 && i < 2) ? 0x3F80 : 0;

    unsigned b0a = 0xFFFFFFFFu, b0b = 0xFFFFFFFFu;
    unsigned b1a = 0xFFFFFFFFu, b1b = 0xFFFFFFFFu;

    for (int kc = 0; kc < 16; ++kc) {
        const int cur = kc & 1;
        if (kc < 15) {
            stage(kc + 1, cur ^ 1);
            asm volatile("s_waitcnt vmcnt(4)" ::: "memory");   // this round landed
        } else {
            asm volatile("s_waitcnt vmcnt(0)" ::: "memory");
        }
        __builtin_amdgcn_s_barrier();
        __builtin_amdgcn_sched_barrier(0);

        const unsigned d = cnl[kh * 512 + kc * 32 + ln31];
        #pragma unroll
        for (int i = 0; i < 8; ++i) cfr0.u[i] = 0;
        if (hi == 0) {
            cfr0.u[0] = (unsigned short)(d & 0xFFFFu);
            cfr0.u[1] = (unsigned short)(d >> 16);
        }

        f32x16 acc0, acc1;
        #pragma unroll
        for (int i = 0; i < 16; ++i) { acc0[i] = 0.0f; acc1[i] = 0.0f; }
        acc0 = __builtin_amdgcn_mfma_f32_32x32x16_bf16(cfr0.v, onef.v, acc0, 0, 0, 0);
        acc1 = __builtin_amdgcn_mfma_f32_32x32x16_bf16(cfr0.v, onef.v, acc1, 0, 0, 0);

        // A frags: per window 2 contiguous-512B b128 reads (conflict-free)
        const char* cbpA = ring + cur * 16384 + kh * 8192 + hi * 1024 + ln31 * 16;
        #pragma unroll
        for (int wnd = 0; wnd < 4; ++wnd) {
            const uint4 alo = *reinterpret_cast<const uint4*>(cbpA + wnd * 2048);
            const uint4 ahi = *reinterpret_cast<const uint4*>(cbpA + wnd * 2048 + 512);
            i32x8 aw;
            aw[0] = (int)alo.x; aw[1] = (int)alo.y; aw[2] = (int)alo.z; aw[3] = (int)alo.w;
            aw[4] = (int)ahi.x; aw[5] = (int)ahi.y; aw[6] = (int)ahi.z; aw[7] = (int)ahi.w;
            acc0 = __builtin_amdgcn_mfma_scale_f32_32x32x64_f8f6f4(
                aw, xf0[wnd], acc0, 0, 0, 0, 0x7F7F7F7F, 0, 0x7F7F7F7F);
            acc1 = __builtin_amdgcn_mfma_scale_f32_32x32x64_f8f6f4(
                aw, xf1[wnd], acc1, 0, 0, 0, 0x7F7F7F7F, 0, 0x7F7F7F7F);
        }

        const int kbl = kh * 512 + kc * 32 + hi * 4;
        #pragma unroll
        for (int rg = 0; rg < 16; ++rg) {
            const unsigned kk = (unsigned)(kbl + (rg & 3) + 8 * (rg >> 2));
            const unsigned p0 = (f2u(acc0[rg]) & 0xFFFFFC00u) | kk;
            const unsigned p1 = (f2u(acc1[rg]) & 0xFFFFFC00u) | kk;
            if (rg & 1) { b0b = umin2(b0b, p0); b1b = umin2(b1b, p1); }
            else        { b0a = umin2(b0a, p0); b1a = umin2(b1a, p1); }
        }
        __builtin_amdgcn_s_barrier();
        __builtin_amdgcn_sched_barrier(0);
    }

    // merge chains + hi-halves
    unsigned best0 = umin2(b0a, b0b);
    unsigned best1 = umin2(b1a, b1b);
    best0 = umin2(best0, __shfl_xor(best0, 32));
    best1 = umin2(best1, __shfl_xor(best1, 32));
    if (hi == 0) { kbx[w][ln31] = best0; kbx[w][32 + ln31] = best1; }
    __syncthreads();

    float red = x2s;
    if (kh == 0) {                    // merge K-halves; token = tw0 + tg*64 + lane
        const unsigned key = umin2(kbx[w][lane], kbx[w + 1][lane]);
        kkl[tg * 64 + lane] = (int)(key & 1023u);
        red += (u2f(key & 0xFFFFFC00u) - 128.0f) * 0.0078125f;
    }
    #pragma unroll
    for (int off = 32; off; off >>= 1) red += __shfl_down(red, off);
    if (lane == 0) wsum[w] = red;
    __syncthreads();
    if (tid == 0)
        atomicAdd(loss, (wsum[0] + wsum[1] + wsum[2] + wsum[3]) * (2.0f / (float)NELEM));

    // ---- fused scatter: 8 slices of 32 c through [32][132] f32 tile ----
    float* fs = (float*)ring;
    const int tt = tid & 127, ch = tid >> 7;
    const size_t rowb = (size_t)kkl[tt] * DIM;
    #pragma unroll 1
    for (int sl = 0; sl < 8; ++sl) {
        float4 g[4];
        #pragma unroll
        for (int i = 0; i < 4; ++i)
            g[i] = *reinterpret_cast<const float4*>(cbf + rowb + sl * 32 + ch * 16 + 4 * i);
        __syncthreads();
        #pragma unroll
        for (int i = 0; i < 4; ++i) {
            const int c0 = ch * 16 + 4 * i;
            fs[(c0 + 0) * 132 + tt] = g[i].x;
            fs[(c0 + 1) * 132 + tt] = g[i].y;
            fs[(c0 + 2) * 132 + tt] = g[i].z;
            fs[(c0 + 3) * 132 + tt] = g[i].w;
        }
        __syncthreads();
        #pragma unroll
        for (int p = 0; p < 4; ++p) {
            const int c = tid >> 3, tq = (tid & 7) + p * 8;
            const float4 v = *reinterpret_cast<const float4*>(fs + c * 132 + tq * 4);
            *reinterpret_cast<float4*>(
                out + (((size_t)(b * DIM + sl * 32 + c)) << 12) + tb + tq * 4) = v;
        }
    }
}

extern "C" void kernel_launch(void* const* d_in, const int* in_sizes, int n_in,
                              void* d_out, int out_size, void* d_ws, size_t ws_size,
                              hipStream_t stream) {
    const float* x  = (const float*)d_in[0];    // [16,256,4096]
    const float* cb = (const float*)d_in[1];    // [1024,256]
    float* out = (float*)d_out;                 // quant (16777216) + loss (1)
    unsigned* ws = (unsigned*)d_ws;
    unsigned* cnh2 = ws;                        // 1024 u32
    char* cbb8 = (char*)(ws + 4096);            // 256 KB fp8 codebook (MX-tiled)

    hipMemsetAsync(out + NELEM, 0, 4, stream);  // zero loss accumulator (every call)
    prep<<<K_CODES / 4, 256, 0, stream>>>(cb, cbb8, cnh2);
    vq_fused<<<N_TOK / 128, 256, 0, stream>>>(x, cbb8, cnh2, cb, out, out + NELEM);
}

// Round 19
// 49.192 us; speedup vs baseline: 1.1559x; 1.0880x over previous
//
#include <hip/hip_runtime.h>

#define DIM 256
#define T_LEN 4096
#define K_CODES 1024
#define N_TOK 65536
#define NELEM 16777216

// ws layout (32-bit units):
//   [0,1024)       cnh2[k] packed (bf16_hi | bf16_lo<<16) of 128 + 128*|e_k|^2
//   [1024,1536)    loss partials (512 f32)
//   [4096,69632)   cbb8: fp8(256*cb), MX-tiled 256 KB:
//                  byte = ci*8192 + wnd*2048 + hs*1024 + half*512 + r*16 + off
//                  code k = ci*32 + r; dim d: wnd=d>>6, dw=d&63, hs=dw>>5,
//                  i=dw&31, half=i>>4, off=i&15.
// Score: s' = 128 + 128|e|^2 - 256*(e_fp8 . x_fp8) in ~[80,180] > 0 (MX scales
// = 1.0 so the dot is plain fp8 arithmetic).

typedef __attribute__((ext_vector_type(8))) short bf16x8;
typedef __attribute__((ext_vector_type(16))) float f32x16;
typedef __attribute__((ext_vector_type(8))) int i32x8;

__device__ __forceinline__ unsigned short f2bf(float f) {     // RNE f32->bf16
    unsigned u = __builtin_bit_cast(unsigned, f);
    return (unsigned short)((u + 0x7FFFu + ((u >> 16) & 1u)) >> 16);
}
__device__ __forceinline__ float bf2f(unsigned short h) {
    return __builtin_bit_cast(float, (unsigned)h << 16);
}
__device__ __forceinline__ unsigned f2u(float f) { return __builtin_bit_cast(unsigned, f); }
__device__ __forceinline__ float u2f(unsigned u) { return __builtin_bit_cast(float, u); }
__device__ __forceinline__ unsigned umin2(unsigned a, unsigned b) { return a < b ? a : b; }

union FragU { bf16x8 v; unsigned short u[8]; };

#define GLLOAD(gsrc, lbase)                                                              \
    __builtin_amdgcn_global_load_lds(                                                    \
        (const __attribute__((address_space(1))) unsigned int*)(gsrc),                   \
        (__attribute__((address_space(3))) unsigned int*)(lbase), 16, 0, 0)

// two f32 -> 2 fp8 e4m3 (bytes 0,1), negated / plain
__device__ __forceinline__ unsigned cvt8n(float a, float b) {
    unsigned r;
    asm("v_cvt_pk_fp8_f32 %0, -%1, -%2" : "=v"(r) : "v"(a), "v"(b));
    return r;
}
__device__ __forceinline__ unsigned cvt8(float a, float b) {
    unsigned r;
    asm("v_cvt_pk_fp8_f32 %0, %1, %2" : "=v"(r) : "v"(a), "v"(b));
    return r;
}

// ---------------- prep: cb -> fp8(256x, MX-tiled) + cnh2 ----------------
__global__ __launch_bounds__(256) void prep(const float* __restrict__ cb,
                                            char* __restrict__ cbb8,
                                            unsigned* __restrict__ cnh2) {
    const int k = blockIdx.x * 4 + (threadIdx.x >> 6);
    const int lane = threadIdx.x & 63;
    float4 v = *reinterpret_cast<const float4*>(cb + (size_t)k * DIM + lane * 4);
    float s = v.x * v.x + v.y * v.y + v.z * v.z + v.w * v.w;
    #pragma unroll
    for (int off = 32; off; off >>= 1) s += __shfl_down(s, off);
    if (lane == 0) {
        float cn = 128.0f + 128.0f * s;               // 128 + 128|e|^2
        unsigned short chi = f2bf(cn);
        unsigned short clo = f2bf(cn - bf2f(chi));
        cnh2[k] = (unsigned)chi | ((unsigned)clo << 16);
    }
    const unsigned wlo = cvt8(256.0f * v.x, 256.0f * v.y);
    const unsigned whi = cvt8(256.0f * v.z, 256.0f * v.w);
    const unsigned dw = __builtin_amdgcn_perm(whi, wlo, 0x05040100u);  // [x,y,z,w]
    const int d0 = lane * 4;
    const int wnd = d0 >> 6, dwi = d0 & 63, hs = dwi >> 5, i = dwi & 31;
    const int byte = (k >> 5) * 8192 + wnd * 2048 + hs * 1024 + (i >> 4) * 512
                   + (k & 31) * 16 + (i & 15);
    *reinterpret_cast<unsigned*>(cbb8 + byte) = dw;
}

// ---------------- fused: MX-fp8 argmin sweep + scatter + loss ----------------
// r14 structure verbatim: 512 blocks x 4 waves (2 tg x 2 kh), 64 tok/wave,
// 16 rounds, counted vmcnt(4) + raw barriers, 2x16KB dbuf staging,
// mfma_scale_f32_32x32x64_f8f6f4 with unit scales, fused scatter.
__global__ __launch_bounds__(256, 2) void vq_fused(const float* __restrict__ x,
                                                   const char* __restrict__ cbb8,
                                                   const unsigned* __restrict__ cnh2,
                                                   const float* __restrict__ cbf,
                                                   float* __restrict__ out,
                                                   float* __restrict__ part) {
    __shared__ __align__(16) char ring[32768];        // x-tile / 2x16KB dbuf / scatter
    __shared__ unsigned cnl[1024];
    __shared__ unsigned kbx[4][64];
    __shared__ int kkl[128];
    __shared__ float wsum[4];
    const int tid = threadIdx.x;
    const int w = tid >> 6, lane = tid & 63, hi = lane >> 5, ln31 = lane & 31;
    const int tg = w >> 1, kh = w & 1;
    const int tw0 = blockIdx.x * 128;
    const int b = tw0 >> 12, tb = tw0 & (T_LEN - 1);

    cnl[tid] = cnh2[tid];
    cnl[tid + 256] = cnh2[tid + 256];
    cnl[tid + 512] = cnh2[tid + 512];
    cnl[tid + 768] = cnh2[tid + 768];

    // ---- x ingest: [128 t][256 d] fp8 tile (32 KB), negated, 8B-granule XOR ----
    const int tqi = tid & 31, cqi = tid >> 5;         // 32 t-quads x 8 c-octs
    const float* xb = x + (size_t)b * DIM * T_LEN + tb + 4 * tqi;
    float x2s = 0.0f;
    #pragma unroll
    for (int ii = 0; ii < 8; ++ii) {
        const int cl = (ii * 8 + cqi) * 4;            // dim quad 0..252
        const float* p = xb + (size_t)cl * T_LEN;
        const float4 P0 = *reinterpret_cast<const float4*>(p);
        const float4 P1 = *reinterpret_cast<const float4*>(p + T_LEN);
        const float4 P2 = *reinterpret_cast<const float4*>(p + 2 * T_LEN);
        const float4 P3 = *reinterpret_cast<const float4*>(p + 3 * T_LEN);
        x2s = fmaf(P0.x, P0.x, fmaf(P0.y, P0.y, fmaf(P0.z, P0.z, fmaf(P0.w, P0.w, x2s))));
        x2s = fmaf(P1.x, P1.x, fmaf(P1.y, P1.y, fmaf(P1.z, P1.z, fmaf(P1.w, P1.w, x2s))));
        x2s = fmaf(P2.x, P2.x, fmaf(P2.y, P2.y, fmaf(P2.z, P2.z, fmaf(P2.w, P2.w, x2s))));
        x2s = fmaf(P3.x, P3.x, fmaf(P3.y, P3.y, fmaf(P3.z, P3.z, fmaf(P3.w, P3.w, x2s))));
        const unsigned lo0 = cvt8n(P0.x, P0.y), hi0 = cvt8n(P0.z, P0.w);
        const unsigned lo1 = cvt8n(P1.x, P1.y), hi1 = cvt8n(P1.z, P1.w);
        const unsigned lo2 = cvt8n(P2.x, P2.y), hi2 = cvt8n(P2.z, P2.w);
        const unsigned lo3 = cvt8n(P3.x, P3.y), hi3 = cvt8n(P3.z, P3.w);
        const unsigned s01 = __builtin_amdgcn_perm(lo1, lo0, 0x05010400u);
        const unsigned s23 = __builtin_amdgcn_perm(lo3, lo2, 0x05010400u);
        const unsigned u01 = __builtin_amdgcn_perm(hi1, hi0, 0x05010400u);
        const unsigned u23 = __builtin_amdgcn_perm(hi3, hi2, 0x05010400u);
        const unsigned t0 = __builtin_amdgcn_perm(s23, s01, 0x05040100u);
        const unsigned t1 = __builtin_amdgcn_perm(s23, s01, 0x07060302u);
        const unsigned t2 = __builtin_amdgcn_perm(u23, u01, 0x05040100u);
        const unsigned t3 = __builtin_amdgcn_perm(u23, u01, 0x07060302u);
        const int ta = 4 * tqi;
        *reinterpret_cast<unsigned*>(ring + (ta + 0) * 256 + (cl ^ (((ta + 0) & 15) << 3))) = t0;
        *reinterpret_cast<unsigned*>(ring + (ta + 1) * 256 + (cl ^ (((ta + 1) & 15) << 3))) = t1;
        *reinterpret_cast<unsigned*>(ring + (ta + 2) * 256 + (cl ^ (((ta + 2) & 15) << 3))) = t2;
        *reinterpret_cast<unsigned*>(ring + (ta + 3) * 256 + (cl ^ (((ta + 3) & 15) << 3))) = t3;
    }
    __syncthreads();

    // ---- xf frags: B-operand, 4 K-windows; lane = (token=l&31, k=(l>>5)*32+i) ----
    i32x8 xf0[4], xf1[4];                             // 64 VGPR total
    {
        const int tp0 = tg * 64 + ln31, tp1 = tg * 64 + 32 + ln31;
        const int z0 = (tp0 & 15) << 3, z1 = (tp1 & 15) << 3;
        #pragma unroll
        for (int wnd = 0; wnd < 4; ++wnd) {
            #pragma unroll
            for (int g = 0; g < 4; ++g) {
                const int o = wnd * 64 + hi * 32 + g * 8;
                const long v0 = *reinterpret_cast<const long*>(ring + tp0 * 256 + (o ^ z0));
                const long v1 = *reinterpret_cast<const long*>(ring + tp1 * 256 + (o ^ z1));
                xf0[wnd][2 * g] = (int)(unsigned)(v0 & 0xFFFFFFFFu);
                xf0[wnd][2 * g + 1] = (int)(unsigned)(((unsigned long)v0) >> 32);
                xf1[wnd][2 * g] = (int)(unsigned)(v1 & 0xFFFFFFFFu);
                xf1[wnd][2 * g + 1] = (int)(unsigned)(((unsigned long)v1) >> 32);
            }
        }
    }
    __syncthreads();                                  // ring free for staging

    // ---- staging: chunks kc (kh0) and 16+kc (kh1) -> 16 KB, linear copy ----
    auto stage = [&](int kc, int buf) {
        char* lb = ring + buf * 16384 + w * 1024;
        const char* gc = cbb8 + kc * 8192;
        #pragma unroll
        for (int j = 0; j < 4; ++j) {
            const int o = j * 4096 + tid * 16;
            GLLOAD(gc + (o & 8191) + (o >> 13) * 131072, lb + j * 4096);
        }
    };
    stage(0, 0);

    FragU cfr0, onef;                                 // bf16 cn-fold operands
    #pragma unroll
    for (int i = 0; i < 8; ++i) onef.u[i] = (hi == 0 && i < 2) ? 0x3F80 : 0;

    unsigned b0a = 0xFFFFFFFFu, b0b = 0xFFFFFFFFu;
    unsigned b1a = 0xFFFFFFFFu, b1b = 0xFFFFFFFFu;

    for (int kc = 0; kc < 16; ++kc) {
        const int cur = kc & 1;
        if (kc < 15) {
            stage(kc + 1, cur ^ 1);
            asm volatile("s_waitcnt vmcnt(4)" ::: "memory");   // this round landed
        } else {
            asm volatile("s_waitcnt vmcnt(0)" ::: "memory");
        }
        __builtin_amdgcn_s_barrier();
        __builtin_amdgcn_sched_barrier(0);

        const unsigned d = cnl[kh * 512 + kc * 32 + ln31];
        #pragma unroll
        for (int i = 0; i < 8; ++i) cfr0.u[i] = 0;
        if (hi == 0) {
            cfr0.u[0] = (unsigned short)(d & 0xFFFFu);
            cfr0.u[1] = (unsigned short)(d >> 16);
        }

        f32x16 acc0, acc1;
        #pragma unroll
        for (int i = 0; i < 16; ++i) { acc0[i] = 0.0f; acc1[i] = 0.0f; }
        acc0 = __builtin_amdgcn_mfma_f32_32x32x16_bf16(cfr0.v, onef.v, acc0, 0, 0, 0);
        acc1 = __builtin_amdgcn_mfma_f32_32x32x16_bf16(cfr0.v, onef.v, acc1, 0, 0, 0);

        // A frags: per window 2 contiguous-512B b128 reads (conflict-free)
        const char* cbpA = ring + cur * 16384 + kh * 8192 + hi * 1024 + ln31 * 16;
        #pragma unroll
        for (int wnd = 0; wnd < 4; ++wnd) {
            const uint4 alo = *reinterpret_cast<const uint4*>(cbpA + wnd * 2048);
            const uint4 ahi = *reinterpret_cast<const uint4*>(cbpA + wnd * 2048 + 512);
            i32x8 aw;
            aw[0] = (int)alo.x; aw[1] = (int)alo.y; aw[2] = (int)alo.z; aw[3] = (int)alo.w;
            aw[4] = (int)ahi.x; aw[5] = (int)ahi.y; aw[6] = (int)ahi.z; aw[7] = (int)ahi.w;
            acc0 = __builtin_amdgcn_mfma_scale_f32_32x32x64_f8f6f4(
                aw, xf0[wnd], acc0, 0, 0, 0, 0x7F7F7F7F, 0, 0x7F7F7F7F);
            acc1 = __builtin_amdgcn_mfma_scale_f32_32x32x64_f8f6f4(
                aw, xf1[wnd], acc1, 0, 0, 0, 0x7F7F7F7F, 0, 0x7F7F7F7F);
        }

        const int kbl = kh * 512 + kc * 32 + hi * 4;
        #pragma unroll
        for (int rg = 0; rg < 16; ++rg) {
            const unsigned kk = (unsigned)(kbl + (rg & 3) + 8 * (rg >> 2));
            const unsigned p0 = (f2u(acc0[rg]) & 0xFFFFFC00u) | kk;
            const unsigned p1 = (f2u(acc1[rg]) & 0xFFFFFC00u) | kk;
            if (rg & 1) { b0b = umin2(b0b, p0); b1b = umin2(b1b, p1); }
            else        { b0a = umin2(b0a, p0); b1a = umin2(b1a, p1); }
        }
        __builtin_amdgcn_s_barrier();
        __builtin_amdgcn_sched_barrier(0);
    }

    // merge chains + hi-halves
    unsigned best0 = umin2(b0a, b0b);
    unsigned best1 = umin2(b1a, b1b);
    best0 = umin2(best0, __shfl_xor(best0, 32));
    best1 = umin2(best1, __shfl_xor(best1, 32));
    if (hi == 0) { kbx[w][ln31] = best0; kbx[w][32 + ln31] = best1; }
    __syncthreads();

    float red = x2s;
    if (kh == 0) {                    // merge K-halves; token = tw0 + tg*64 + lane
        const unsigned key = umin2(kbx[w][lane], kbx[w + 1][lane]);
        kkl[tg * 64 + lane] = (int)(key & 1023u);
        // per-token |e-x|^2 = (s'-128)/128 + |x|^2
        red += (u2f(key & 0xFFFFFC00u) - 128.0f) * 0.0078125f;
    }
    #pragma unroll
    for (int off = 32; off; off >>= 1) red += __shfl_down(red, off);
    if (lane == 0) wsum[w] = red;
    __syncthreads();
    if (tid == 0) part[blockIdx.x] = wsum[0] + wsum[1] + wsum[2] + wsum[3];

    // ---- fused scatter: 8 slices of 32 c through [32][132] f32 tile ----
    float* fs = (float*)ring;
    const int tt = tid & 127, ch = tid >> 7;
    const size_t rowb = (size_t)kkl[tt] * DIM;
    #pragma unroll 1
    for (int sl = 0; sl < 8; ++sl) {
        float4 g[4];
        #pragma unroll
        for (int i = 0; i < 4; ++i)
            g[i] = *reinterpret_cast<const float4*>(cbf + rowb + sl * 32 + ch * 16 + 4 * i);
        __syncthreads();
        #pragma unroll
        for (int i = 0; i < 4; ++i) {
            const int c0 = ch * 16 + 4 * i;
            fs[(c0 + 0) * 132 + tt] = g[i].x;
            fs[(c0 + 1) * 132 + tt] = g[i].y;
            fs[(c0 + 2) * 132 + tt] = g[i].z;
            fs[(c0 + 3) * 132 + tt] = g[i].w;
        }
        __syncthreads();
        #pragma unroll
        for (int p = 0; p < 4; ++p) {
            const int c = tid >> 3, tq = (tid & 7) + p * 8;
            const float4 v = *reinterpret_cast<const float4*>(fs + c * 132 + tq * 4);
            *reinterpret_cast<float4*>(
                out + (((size_t)(b * DIM + sl * 32 + c)) << 12) + tb + tq * 4) = v;
        }
    }
}

// ---------------- finalize loss ----------------
__global__ __launch_bounds__(256) void finalize(const float* __restrict__ part,
                                                float* __restrict__ loss_out) {
    double s = (double)part[threadIdx.x] + (double)part[threadIdx.x + 256];
    #pragma unroll
    for (int off = 32; off; off >>= 1) s += __shfl_down(s, off);
    __shared__ double wsum[4];
    const int lane = threadIdx.x & 63, wv = threadIdx.x >> 6;
    if (lane == 0) wsum[wv] = s;
    __syncthreads();
    if (threadIdx.x == 0)
        *loss_out = (float)(2.0 * (wsum[0] + wsum[1] + wsum[2] + wsum[3]) / (double)NELEM);
}

extern "C" void kernel_launch(void* const* d_in, const int* in_sizes, int n_in,
                              void* d_out, int out_size, void* d_ws, size_t ws_size,
                              hipStream_t stream) {
    const float* x  = (const float*)d_in[0];    // [16,256,4096]
    const float* cb = (const float*)d_in[1];    // [1024,256]
    float* out = (float*)d_out;                 // quant (16777216) + loss (1)
    unsigned* ws = (unsigned*)d_ws;
    unsigned* cnh2 = ws;                        // 1024 u32
    float* part = (float*)(ws + 1024);          // 512 f32
    char* cbb8 = (char*)(ws + 4096);            // 256 KB fp8 codebook (MX-tiled)

    prep<<<K_CODES / 4, 256, 0, stream>>>(cb, cbb8, cnh2);
    vq_fused<<<N_TOK / 128, 256, 0, stream>>>(x, cbb8, cnh2, cb, out, part);
    finalize<<<1, 256, 0, stream>>>(part, out + NELEM);
}